// Round 5
// baseline (267.071 us; speedup 1.0000x reference)
//
#include <hip/hip_runtime.h>
#include <math.h>

#define T_FRAMES 16384
#define FDIM 2048
#define LQ 30
#define FPB 8    // frames per block (2 per wave, 4 waves)

// ---------------------------------------------------------------------------
// Kernel 0: precompute per-head 7x7 bilinear forms
//   A_h[c][c2] = sum_d W_q[h*64+d][c] * W_k[h*64+d][c2]
//   M_h[c][c2] = sum_d W_o[c][h*64+d] * W_v[h*64+d][c2]
// AM layout: [0..195] = A (h*49 + c*7 + c2), [196..391] = M
// (proven in R1/R3 incl. post-timing validation — do not touch)
// ---------------------------------------------------------------------------
__global__ __launch_bounds__(448) void setup_kernel(
    const float* __restrict__ Wq, const float* __restrict__ Wk,
    const float* __restrict__ Wv, const float* __restrict__ Wo,
    float* __restrict__ AM) {
  const int e = threadIdx.x;
  if (e >= 392) return;
  const int which = e / 196;
  const int r = e % 196;
  const int h = r / 49;
  const int rr = r % 49;
  const int c = rr / 7;
  const int c2 = rr % 7;
  float s = 0.0f;
  if (which == 0) {
    for (int d = 0; d < 64; ++d)
      s = fmaf(Wq[(h * 64 + d) * 7 + c], Wk[(h * 64 + d) * 7 + c2], s);
  } else {
    for (int d = 0; d < 64; ++d)
      s = fmaf(Wo[c * 256 + h * 64 + d], Wv[(h * 64 + d) * 7 + c2], s);
  }
  AM[e] = s;
}

// ---------------------------------------------------------------------------
// Fused kernel: R3 structure, FPB=8 (2 frames/wave -> fewer acc regs, more
// waves/SIMD, 2048 blocks). NO forced min-occupancy (R4's (256,6) caused a
// spill-related post-timing failure), NO manual prefetch.
// ---------------------------------------------------------------------------
__global__ __launch_bounds__(256) void fused_kernel(
    const float* __restrict__ lf,    // (T, 2048)
    const float* __restrict__ Wfc,   // (7, 2048)
    const float* __restrict__ x,     // (7, T)
    const float* __restrict__ AM,    // 392
    const float* __restrict__ W1,    // (64, 7)
    const float* __restrict__ W2,    // (7, 64)
    const float* __restrict__ ln1g, const float* __restrict__ ln1b,
    const float* __restrict__ ln2g, const float* __restrict__ ln2b,
    float* __restrict__ out) {       // (T, 7)
  __shared__ float feas_s[FPB][7];
  __shared__ float AM_s[392];
  __shared__ float ft[(FPB + LQ - 1) * 7];   // 37 rows x 7
  __shared__ float hpart[FPB][4][7];

  const int tid = threadIdx.x;
  const int lane = tid & 63;
  const int wave = tid >> 6;
  const int t0 = blockIdx.x * FPB;

  // stage AM (strided: 392 > 256) and the feats window (37 x 7)
  for (int i = tid; i < 392; i += 256) AM_s[i] = AM[i];
  for (int i = tid; i < (FPB + LQ - 1) * 7; i += 256) {
    const int row = i / 7, c = i % 7;
    const int s = t0 - (LQ - 1) + row;
    ft[i] = (s >= 0) ? x[c * T_FRAMES + s] : 0.0f;
  }

  // ---- phase 1: feas, 2 frames per wave ----
  const int tf = t0 + wave * 2;                 // wave-uniform
  const float* lfp0 = lf + (size_t)tf * FDIM;
  const float* lfp1 = lfp0 + FDIM;
  const int fl = lane * 4;

  float acc0[7], acc1[7];
#pragma unroll
  for (int c = 0; c < 7; ++c) { acc0[c] = 0.0f; acc1[c] = 0.0f; }

  for (int chunk = 0; chunk < 8; ++chunk) {
    const int f = chunk * 256 + fl;
    const float4 a0 = *(const float4*)(lfp0 + f);
    const float4 a1 = *(const float4*)(lfp1 + f);
#pragma unroll
    for (int c = 0; c < 7; ++c) {
      const float4 w = *(const float4*)(Wfc + c * FDIM + f);
      acc0[c] = fmaf(a0.x, w.x, fmaf(a0.y, w.y, fmaf(a0.z, w.z, fmaf(a0.w, w.w, acc0[c]))));
      acc1[c] = fmaf(a1.x, w.x, fmaf(a1.y, w.y, fmaf(a1.z, w.z, fmaf(a1.w, w.w, acc1[c]))));
    }
  }

#pragma unroll
  for (int c = 0; c < 7; ++c) {
    float v0 = acc0[c], v1 = acc1[c];
    for (int off = 32; off > 0; off >>= 1) {
      v0 += __shfl_down(v0, off, 64);
      v1 += __shfl_down(v1, off, 64);
    }
    if (lane == 0) {
      feas_s[wave * 2 + 0][c] = tanhf(v0);
      feas_s[wave * 2 + 1][c] = tanhf(v1);
    }
  }
  __syncthreads();

  // ---- phase 2a: (frame, head) lanes ----
  if (tid < FPB * 4) {
    const int f = tid >> 2;   // local frame
    const int h = tid & 3;    // head
    float fe[7];
#pragma unroll
    for (int c = 0; c < 7; ++c) fe[c] = feas_s[f][c];

    const float* Ah = AM_s + h * 49;
    const float* Mh = AM_s + 196 + h * 49;
    float qk[7];
#pragma unroll
    for (int c2 = 0; c2 < 7; ++c2) {
      float s = 0.0f;
#pragma unroll
      for (int c = 0; c < 7; ++c) s = fmaf(fe[c], Ah[c * 7 + c2], s);
      qk[c2] = s * 0.125f;
    }
    const float* frow = &ft[f * 7];
    float sc[LQ];
    float m = -1e30f;
#pragma unroll
    for (int j = 0; j < LQ; ++j) {
      const float* r = frow + j * 7;
      float s = 0.0f;
#pragma unroll
      for (int c2 = 0; c2 < 7; ++c2) s = fmaf(qk[c2], r[c2], s);
      sc[j] = s;
      m = fmaxf(m, s);
    }
    float sum = 0.0f;
    float wsum[7] = {0, 0, 0, 0, 0, 0, 0};
#pragma unroll
    for (int j = 0; j < LQ; ++j) {
      const float p = __expf(sc[j] - m);
      sum += p;
      const float* r = frow + j * 7;
#pragma unroll
      for (int c2 = 0; c2 < 7; ++c2) wsum[c2] = fmaf(p, r[c2], wsum[c2]);
    }
    const float inv = 1.0f / sum;
#pragma unroll
    for (int c = 0; c < 7; ++c) {
      float s = 0.0f;
#pragma unroll
      for (int c2 = 0; c2 < 7; ++c2) s = fmaf(Mh[c * 7 + c2], wsum[c2], s);
      hpart[f][h][c] = s * inv;
    }
  }
  __syncthreads();

  // ---- phase 2b: per-frame epilogue ----
  if (tid < FPB) {
    const int f = tid;
    float v[7];
#pragma unroll
    for (int c = 0; c < 7; ++c)
      v[c] = feas_s[f][c] + hpart[f][0][c] + hpart[f][1][c] + hpart[f][2][c] + hpart[f][3][c];

    float mu = 0.0f;
#pragma unroll
    for (int c = 0; c < 7; ++c) mu += v[c];
    mu *= (1.0f / 7.0f);
    float var = 0.0f;
#pragma unroll
    for (int c = 0; c < 7; ++c) { const float d = v[c] - mu; var = fmaf(d, d, var); }
    var *= (1.0f / 7.0f);
    float rs = rsqrtf(var + 1e-5f);
    float o1[7];
#pragma unroll
    for (int c = 0; c < 7; ++c) o1[c] = (v[c] - mu) * rs * ln1g[c] + ln1b[c];

    float ff[7] = {0, 0, 0, 0, 0, 0, 0};
    for (int k = 0; k < 64; ++k) {
      float hk = 0.0f;
#pragma unroll
      for (int c = 0; c < 7; ++c) hk = fmaf(W1[k * 7 + c], o1[c], hk);
      hk = fmaxf(hk, 0.0f);
#pragma unroll
      for (int c = 0; c < 7; ++c) ff[c] = fmaf(W2[c * 64 + k], hk, ff[c]);
    }

#pragma unroll
    for (int c = 0; c < 7; ++c) v[c] = ff[c] + o1[c];
    mu = 0.0f;
#pragma unroll
    for (int c = 0; c < 7; ++c) mu += v[c];
    mu *= (1.0f / 7.0f);
    var = 0.0f;
#pragma unroll
    for (int c = 0; c < 7; ++c) { const float d = v[c] - mu; var = fmaf(d, d, var); }
    var *= (1.0f / 7.0f);
    rs = rsqrtf(var + 1e-5f);
    const int t = t0 + f;
#pragma unroll
    for (int c = 0; c < 7; ++c)
      out[(size_t)t * 7 + c] = (v[c] - mu) * rs * ln2g[c] + ln2b[c];
  }
}

// ---------------------------------------------------------------------------
extern "C" void kernel_launch(void* const* d_in, const int* in_sizes, int n_in,
                              void* d_out, int out_size, void* d_ws, size_t ws_size,
                              hipStream_t stream) {
  const float* x    = (const float*)d_in[0];   // (1, 7, T)
  const float* lf   = (const float*)d_in[1];   // (1, T, 2048)
  const float* Wfc  = (const float*)d_in[2];   // (7, 2048)
  const float* Wq   = (const float*)d_in[3];   // (256, 7)
  const float* Wk   = (const float*)d_in[4];   // (256, 7)
  const float* Wv   = (const float*)d_in[5];   // (256, 7)
  const float* Wo   = (const float*)d_in[6];   // (7, 256)
  const float* ln1g = (const float*)d_in[7];
  const float* ln1b = (const float*)d_in[8];
  const float* W1   = (const float*)d_in[9];   // (64, 7)
  const float* W2   = (const float*)d_in[10];  // (7, 64)
  const float* ln2g = (const float*)d_in[11];
  const float* ln2b = (const float*)d_in[12];
  float* out = (float*)d_out;

  float* AM = (float*)d_ws;   // 392 floats

  setup_kernel<<<1, 448, 0, stream>>>(Wq, Wk, Wv, Wo, AM);
  fused_kernel<<<T_FRAMES / FPB, 256, 0, stream>>>(
      lf, Wfc, x, AM, W1, W2, ln1g, ln1b, ln2g, ln2b, out);
}